// Round 4
// baseline (761.621 us; speedup 1.0000x reference)
//
#include <hip/hip_runtime.h>
#include <hip/hip_bf16.h>

// Qriaffine: out[n,i,j] = sum_{a,b,c,d} l1[n,i,a] W[a,b,c,d] l2[n,j,b] h1[n,i,c] h2[n,j,d]
//
// R4: ALL GEMM operands stored in MFMA-fragment order -> K-loop is pure
// global_load_dwordx4 (1KB coalesced, cache-served) + mfma. No LDS, no
// __syncthreads in the main loop (the LDS pipe was carrying 96KB/block-iter
// = ~70% of wall time in R3). GEMM1 writes Q in fragment layout via a
// one-time LDS transpose epilogue so GEMM2 uses the same barrier-free kernel.
//
// Fragment layout for matrix X (R_ rows, K_ k): frag (rb, kc) = rows
// [rb*32, rb*32+32) x k [kc*16, kc*16+16), stored as 1KB block:
//   elem index = ((rb*(K_/16) + kc)*64 + lane)*8 + e
//   lane&31 = row%32, lane>>5 = (k%16)/8, e = k%8   (matches 32x32x16 A/B frag)

typedef __attribute__((ext_vector_type(8))) short short8;     // 8 bf16 = 4 VGPRs
typedef __attribute__((ext_vector_type(16))) float floatx16;  // MFMA 32x32 acc

#define KP 4288    // padded (a,c) dim: 268*16
#define DP 4352    // padded (b,d) dim: 272*16
#define NROW 8192  // n*L
#define K16P 268
#define K16D 272

// ---------------- zero helper (16B granularity) ----------------
__global__ void zero_kernel(float4* __restrict__ p, long n) {
  long i = (long)blockIdx.x * blockDim.x + threadIdx.x;
  long stride = (long)gridDim.x * blockDim.x;
  float4 z = make_float4(0.f, 0.f, 0.f, 0.f);
  for (; i < n; i += stride) p[i] = z;
}

// ---------------- W[a,b,c,d] -> Wt2 fragment layout ----------------
// B-row = b*65+d (pad 4352), k = a*65+c (pad 4288). Pads pre-zeroed.
__global__ void build_wt2f(const float* __restrict__ W, __hip_bfloat16* __restrict__ Bf) {
  const int a = blockIdx.x, b = blockIdx.y;
  const float* src = W + (size_t)(a * 65 + b) * 4225;  // contiguous (c,d) plane
  for (int idx = threadIdx.x; idx < 4225; idx += 256) {
    int c = idx / 65, d = idx - c * 65;
    int bd = b * 65 + d;
    int ac = a * 65 + c;
    int lanef = (bd & 31) + ((ac >> 3) & 1) * 32;
    size_t e = ((size_t)((bd >> 5) * K16P + (ac >> 4)) * 64 + lanef) * 8 + (ac & 7);
    Bf[e] = __float2bfloat16(src[idx]);
  }
}

// ---------------- P/R builder, fragment layout ----------------
// P[row][x*65+y] = layer_row[x]*h_row[y] (x==64 -> bias 1). One block = one
// 32-row fragment-block; pad k-cols (>=4225) written as 0.
__global__ void build_pf(const float* __restrict__ layer, const float* __restrict__ h,
                         __hip_bfloat16* __restrict__ Pf, int K16) {
  const int rb = blockIdx.x;
  const int r0 = rb * 32;
  __shared__ float lv[32][65];
  __shared__ float hv[32][65];
  const int t = threadIdx.x;
  for (int i = t; i < 32 * 64; i += 256)
    lv[i >> 6][i & 63] = layer[(size_t)(r0 + (i >> 6)) * 64 + (i & 63)];
  if (t < 32) lv[t][64] = 1.0f;
  for (int i = t; i < 32 * 65; i += 256) {
    int rr = i / 65, y = i - rr * 65;
    hv[rr][y] = h[(size_t)(r0 + rr) * 65 + y];
  }
  __syncthreads();
  const int lane = t & 63;
  const int rl = lane & 31;  // row within 32-block
  const int kh = lane >> 5;  // k-half
  for (int kc = t >> 6; kc < K16; kc += 4) {
    alignas(16) __hip_bfloat16 tmp[8];
#pragma unroll
    for (int e = 0; e < 8; ++e) {
      int k = kc * 16 + kh * 8 + e;
      float v = 0.f;
      if (k < 4225) {
        int x = k / 65, y = k - x * 65;
        v = lv[rl][x] * hv[rl][y];
      }
      tmp[e] = __float2bfloat16(v);
    }
    *(float4*)(Pf + ((size_t)(rb * K16 + kc) * 64 + lane) * 8) = *(const float4*)tmp;
  }
}

// ---------------- fragment-layout NT GEMM, no LDS in main loop ----------------
// A: (M rows, K) frag layout; B: (N rows, K) frag layout. Block = 128x128,
// 4 waves as 2x2, each wave 64x64 = 2x2 tiles of mfma_f32_32x32x16_bf16.
// STORE_FRAG=1: C written bf16 in frag layout (k-dim = N), via LDS transpose.
// STORE_FRAG=0: C written f32 row-major (ldc = cparam).
extern __shared__ char smem_[];
template <int STORE_FRAG>
__global__ __launch_bounds__(256, 2) void gemm_frag(
    const __hip_bfloat16* __restrict__ A, const __hip_bfloat16* __restrict__ B,
    void* __restrict__ Cv, int K16, int cparam, long sA, long sB, long sC) {
  const int z = blockIdx.z;
  const __hip_bfloat16* Ab = A + (size_t)z * sA;
  const __hip_bfloat16* Bb = B + (size_t)z * sB;
  const int t = threadIdx.x;
  const int lane = t & 63;
  const int wave = t >> 6;
  const size_t rbA = (size_t)blockIdx.y * 4 + (wave >> 1) * 2;
  const size_t rbB = (size_t)blockIdx.x * 4 + (wave & 1) * 2;
  const __hip_bfloat16* pA0 = Ab + (rbA * K16 * 64 + lane) * 8;
  const __hip_bfloat16* pA1 = pA0 + (size_t)K16 * 512;
  const __hip_bfloat16* pB0 = Bb + (rbB * K16 * 64 + lane) * 8;
  const __hip_bfloat16* pB1 = pB0 + (size_t)K16 * 512;

  floatx16 acc[2][2] = {};

  for (int kc = 0; kc < K16; kc += 4) {
    const size_t off = (size_t)kc * 512;  // elements
    short8 a0[4], a1[4], b0[4], b1[4];
#pragma unroll
    for (int ks = 0; ks < 4; ++ks) {
      a0[ks] = *(const short8*)(pA0 + off + ks * 512);
      a1[ks] = *(const short8*)(pA1 + off + ks * 512);
      b0[ks] = *(const short8*)(pB0 + off + ks * 512);
      b1[ks] = *(const short8*)(pB1 + off + ks * 512);
    }
#pragma unroll
    for (int ks = 0; ks < 4; ++ks) {
      acc[0][0] = __builtin_amdgcn_mfma_f32_32x32x16_bf16(a0[ks], b0[ks], acc[0][0], 0, 0, 0);
      acc[0][1] = __builtin_amdgcn_mfma_f32_32x32x16_bf16(a0[ks], b1[ks], acc[0][1], 0, 0, 0);
      acc[1][0] = __builtin_amdgcn_mfma_f32_32x32x16_bf16(a1[ks], b0[ks], acc[1][0], 0, 0, 0);
      acc[1][1] = __builtin_amdgcn_mfma_f32_32x32x16_bf16(a1[ks], b1[ks], acc[1][1], 0, 0, 0);
    }
  }

  // C/D layout (verified m74/m101): col = lane&31, row = (reg&3)+8*(reg>>2)+4*(lane>>5)
  const int l31 = lane & 31, lhi = lane >> 5;
  const int wm = (wave >> 1) * 64, wn = (wave & 1) * 64;
  if (STORE_FRAG) {
    // one-time LDS transpose: C-layout regs -> fragment layout (k-dim = cols)
    __hip_bfloat16* lsq = (__hip_bfloat16*)smem_;  // 128 x 136 bf16 = 34816 B
#pragma unroll
    for (int mt = 0; mt < 2; ++mt)
#pragma unroll
      for (int nt = 0; nt < 2; ++nt)
#pragma unroll
        for (int reg = 0; reg < 16; ++reg) {
          int row = wm + mt * 32 + 4 * lhi + (reg & 3) + 8 * (reg >> 2);
          int col = wn + nt * 32 + l31;
          lsq[row * 136 + col] = __float2bfloat16(acc[mt][nt][reg]);
        }
    __syncthreads();
    __hip_bfloat16* Cq = (__hip_bfloat16*)Cv;
    const int CK16 = cparam;  // C's k-chunk count (= N/16 of gemm1)
#pragma unroll
    for (int i = 0; i < 8; ++i) {
      int f = wave * 8 + i;       // 32 fragments in this 128x128 tile
      int rbl = f >> 3, kcl = f & 7;
      short8 v = *(const short8*)(&lsq[(rbl * 32 + l31) * 136 + kcl * 16 + lhi * 8]);
      size_t rbQ = (size_t)blockIdx.y * 4 + rbl;
      size_t kcQ = (size_t)blockIdx.x * 8 + kcl;
      *(short8*)(Cq + (rbQ * CK16 + kcQ) * 512 + lane * 8) = v;
    }
  } else {
    float* C = (float*)Cv + (size_t)z * sC;
    const int ldc = cparam;
    const int bm = blockIdx.y * 128, bn = blockIdx.x * 128;
#pragma unroll
    for (int mt = 0; mt < 2; ++mt)
#pragma unroll
      for (int nt = 0; nt < 2; ++nt)
#pragma unroll
        for (int reg = 0; reg < 16; ++reg) {
          int row = bm + wm + mt * 32 + (reg & 3) + 8 * (reg >> 2) + 4 * lhi;
          int col = bn + wn + nt * 32 + l31;
          C[(size_t)row * ldc + col] = acc[mt][nt][reg];
        }
  }
}

extern "C" void kernel_launch(void* const* d_in, const int* in_sizes, int n_in,
                              void* d_out, int out_size, void* d_ws, size_t ws_size,
                              hipStream_t stream) {
  const float* layer1 = (const float*)d_in[0];
  const float* layer2 = (const float*)d_in[1];
  const float* h1 = (const float*)d_in[3];
  const float* h2 = (const float*)d_in[4];
  const float* W = (const float*)d_in[6];
  float* out = (float*)d_out;

  // workspace (same footprint as R3, high-water 178,880,512 B):
  //   [0 .. 70,254,592)            Pf (8192x4288 bf16, frag)  -- reused for Rf
  //   [70,254,592 .. 107,577,344)  Wt2f (4352x4288 bf16, frag)
  //   [107,577,344 .. 178,880,512) Qf (8192x4352 bf16, frag)
  char* ws = (char*)d_ws;
  __hip_bfloat16* Pf = (__hip_bfloat16*)(ws);
  __hip_bfloat16* Wt2f = (__hip_bfloat16*)(ws + 70254592ULL);
  __hip_bfloat16* Qf = (__hip_bfloat16*)(ws + 107577344ULL);
  __hip_bfloat16* Rf = (__hip_bfloat16*)(ws);  // reuses Pf region after gemm1

  // 1) zero Wt2f (pad rows/cols; real entries overwritten next)
  zero_kernel<<<2048, 256, 0, stream>>>((float4*)Wt2f, 37044224LL / 16);
  // 2) W -> fragment layout
  build_wt2f<<<dim3(65, 65), 256, 0, stream>>>(W, Wt2f);
  // 3) Pf
  build_pf<<<NROW / 32, 256, 0, stream>>>(layer1, h1, Pf, K16P);
  // 4) Qf = Pf @ Wt2f (NT): M=8192, N=4352, K=4288; C in frag layout (CK16=272)
  gemm_frag<1><<<dim3(DP / 128, NROW / 128, 1), 256, 34816, stream>>>(
      Pf, Wt2f, Qf, K16P, K16D, 0, 0, 0);
  // 5) Rf (over the now-dead Pf region)
  build_pf<<<NROW / 32, 256, 0, stream>>>(layer2, h2, Rf, K16D);
  // 6) out_n = Qf_n @ Rf_n^T: M=N=1024, K=4352, batched over n=8; f32 row-major
  gemm_frag<0><<<dim3(1024 / 128, 1024 / 128, 8), 256, 0, stream>>>(
      Qf, Rf, out, K16D, 1024, 1024L * DP, 1024L * DP, 1024L * 1024);
}

// Round 5
// 661.931 us; speedup vs baseline: 1.1506x; 1.1506x over previous
//
#include <hip/hip_runtime.h>
#include <hip/hip_bf16.h>

// Qriaffine: out[n,i,j] = sum_{a,b,c,d} l1[n,i,a] W[a,b,c,d] l2[n,j,b] h1[n,i,c] h2[n,j,d]
//
// R5: all operands in MFMA-fragment layout in GLOBAL memory (R4, verified) but
// staged through LDS in whole 1KB fragment blocks via global_load_lds
// (dedup of R3 + conflict-free stride-1 LDS of R4):
//   - DMA source: contiguous 1KB per instr (perfect coalescing)
//   - DMA dest:   contiguous frag block (wave-uniform base + lane*16)
//   - frag reads: ds_read_b128 stride-1, conflict-free (m134: 12 cyc)
// 128x128 wave tiles (MT=NT=4): 0.5 KB LDS reads per MFMA -> LDS pipe ~= MFMA
// pipe. BK=32 double-buffer = 64 KB LDS, one barrier/iter, DMA(it+1) issued
// after the barrier (vmcnt(0) drain at the NEXT barrier = the pipeline wait).
//
// Fragment layout for X (rows, K16=K/16): frag (g, kc) = rows [g*32,+32) x
// k [kc*16,+16), 1KB block: elem = ((g*K16 + kc)*64 + lane)*8 + e with
// lane&31 = row%32, lane>>5 = (k%16)/8, e = k%8.

typedef __attribute__((ext_vector_type(8))) short short8;     // 8 bf16
typedef __attribute__((ext_vector_type(16))) float floatx16;  // 32x32 acc

#define KP 4288    // padded (a,c): 268*16
#define DP 4352    // padded (b,d): 272*16
#define NROW 8192  // n*L
#define K16P 268
#define K16D 272

__device__ __forceinline__ void async_ld16(const void* g, void* l) {
  __builtin_amdgcn_global_load_lds(
      (const __attribute__((address_space(1))) unsigned int*)g,
      (__attribute__((address_space(3))) unsigned int*)l, 16, 0, 0);
}

// ---------------- zero helper ----------------
__global__ void zero_kernel(float4* __restrict__ p, long n) {
  long i = (long)blockIdx.x * blockDim.x + threadIdx.x;
  long stride = (long)gridDim.x * blockDim.x;
  float4 z = make_float4(0.f, 0.f, 0.f, 0.f);
  for (; i < n; i += stride) p[i] = z;
}

// ---------------- W[a,b,c,d] -> Wt2 fragment layout (verified R4) ----------------
__global__ void build_wt2f(const float* __restrict__ W, __hip_bfloat16* __restrict__ Bf) {
  const int a = blockIdx.x, b = blockIdx.y;
  const float* src = W + (size_t)(a * 65 + b) * 4225;  // contiguous (c,d) plane
  for (int idx = threadIdx.x; idx < 4225; idx += 256) {
    int c = idx / 65, d = idx - c * 65;
    int bd = b * 65 + d;
    int ac = a * 65 + c;
    int lanef = (bd & 31) + ((ac >> 3) & 1) * 32;
    size_t e = ((size_t)((bd >> 5) * K16P + (ac >> 4)) * 64 + lanef) * 8 + (ac & 7);
    Bf[e] = __float2bfloat16(src[idx]);
  }
}

// ---------------- P/R builder, fragment layout (verified R4) ----------------
__global__ void build_pf(const float* __restrict__ layer, const float* __restrict__ h,
                         __hip_bfloat16* __restrict__ Pf, int K16) {
  const int rb = blockIdx.x;
  const int r0 = rb * 32;
  __shared__ float lv[32][65];
  __shared__ float hv[32][65];
  const int t = threadIdx.x;
  for (int i = t; i < 32 * 64; i += 256)
    lv[i >> 6][i & 63] = layer[(size_t)(r0 + (i >> 6)) * 64 + (i & 63)];
  if (t < 32) lv[t][64] = 1.0f;
  for (int i = t; i < 32 * 65; i += 256) {
    int rr = i / 65, y = i - rr * 65;
    hv[rr][y] = h[(size_t)(r0 + rr) * 65 + y];
  }
  __syncthreads();
  const int lane = t & 63;
  const int rl = lane & 31;
  const int kh = lane >> 5;
  for (int kc = t >> 6; kc < K16; kc += 4) {
    alignas(16) __hip_bfloat16 tmp[8];
#pragma unroll
    for (int e = 0; e < 8; ++e) {
      int k = kc * 16 + kh * 8 + e;
      float v = 0.f;
      if (k < 4225) {
        int x = k / 65, y = k - x * 65;
        v = lv[rl][x] * hv[rl][y];
      }
      tmp[e] = __float2bfloat16(v);
    }
    *(float4*)(Pf + ((size_t)(rb * K16 + kc) * 64 + lane) * 8) = *(const float4*)tmp;
  }
}

// ---------------- frag-staged NT GEMM ----------------
// Block = 64*MT (m) x 64*NT (n), 4 waves as 2x2, wave tile 32*MT x 32*NT of
// mfma_f32_32x32x16_bf16. BK=32 (2 kc per iter). Double-buffered LDS.
// STORE_FRAG=1: C bf16 frag layout (k-dim = global N), CK16 = ck16_or_ldc.
// STORE_FRAG=0: C f32 row-major, ldc = ck16_or_ldc.
template <int MT, int NT, int STORE_FRAG>
__global__ __launch_bounds__(256, 1) void gemm_fraglds(
    const __hip_bfloat16* __restrict__ A, const __hip_bfloat16* __restrict__ B,
    void* __restrict__ Cv, int K16, int ck16_or_ldc, int bn0,
    long sA, long sB, long sC) {
  constexpr int FR = 4 * (MT + NT);  // frag blocks per buffer (2 kc * 2(MT+NT) g)
  constexpr int S = FR / 4;          // DMA slots per thread
  constexpr int BUFSZ = FR * 1024;   // bytes per buffer
  __shared__ char smem[2 * BUFSZ];

  const int z = blockIdx.z;
  const __hip_bfloat16* Ab = A + (size_t)z * sA;
  const __hip_bfloat16* Bb = B + (size_t)z * sB;
  const int t = threadIdx.x;
  const int lane = t & 63;
  const int wave = t >> 6;
  const int l31 = lane & 31;
  const int lhi = lane >> 5;
  const int wm_w = wave >> 1;
  const int wn_w = wave & 1;

  const int Ag0 = blockIdx.y * 2 * MT;              // A 32-row group base
  const int Bg0 = (bn0 >> 5) + blockIdx.x * 2 * NT; // B 32-row group base

  // per-lane source base: byte lane*16 within each 1KB frag block
  const __hip_bfloat16* baseA = Ab + lane * 8;
  const __hip_bfloat16* baseB = Bb + lane * 8;

  floatx16 acc[MT][NT] = {};

  const int NIT = K16 >> 1;

  auto issue = [&](int bufsel, int k16_0) {
    char* lds0 = smem + bufsel * BUFSZ;
#pragma unroll
    for (int s = 0; s < S; ++s) {
      int f = s * 4 + wave;  // wave-uniform
      const __hip_bfloat16* src;
      if (f < 4 * MT) {
        src = baseA + ((size_t)(Ag0 + (f >> 1)) * K16 + k16_0 + (f & 1)) * 512;
      } else {
        int f2 = f - 4 * MT;
        src = baseB + ((size_t)(Bg0 + (f2 >> 1)) * K16 + k16_0 + (f2 & 1)) * 512;
      }
      async_ld16(src, lds0 + f * 1024);
    }
  };

  issue(0, 0);
  for (int it = 0; it < NIT; ++it) {
    __syncthreads();  // drains DMA(it) [compiler emits vmcnt(0) before barrier]
    if (it + 1 < NIT) issue((it + 1) & 1, (it + 1) * 2);  // overlaps compute
    const char* pa = smem + (it & 1) * BUFSZ + lane * 16 + wm_w * MT * 2048;
    const char* pb = smem + (it & 1) * BUFSZ + lane * 16 + 4 * MT * 1024 + wn_w * NT * 2048;
#pragma unroll
    for (int ks = 0; ks < 2; ++ks) {
      short8 af[MT], bfr[NT];
#pragma unroll
      for (int mt = 0; mt < MT; ++mt) af[mt] = *(const short8*)(pa + (mt * 2 + ks) * 1024);
#pragma unroll
      for (int nt = 0; nt < NT; ++nt) bfr[nt] = *(const short8*)(pb + (nt * 2 + ks) * 1024);
#pragma unroll
      for (int mt = 0; mt < MT; ++mt)
#pragma unroll
        for (int nt = 0; nt < NT; ++nt)
          acc[mt][nt] = __builtin_amdgcn_mfma_f32_32x32x16_bf16(af[mt], bfr[nt], acc[mt][nt], 0, 0, 0);
    }
  }

  __syncthreads();  // all compute done; smem reusable as epilogue scratch

  // C/D layout (verified m74/m101): col = lane&31, row = (reg&3)+8*(reg>>2)+4*(lane>>5)
  if (STORE_FRAG) {
    constexpr int SCW = 32 * NT + 8;  // scratch row pitch (bf16), pad breaks conflicts
    __hip_bfloat16* sc = (__hip_bfloat16*)smem + wave * 32 * SCW;
    __hip_bfloat16* Cq = (__hip_bfloat16*)Cv;
    const int CK16 = ck16_or_ldc;
    const int gQ0 = blockIdx.y * 2 * MT + wm_w * MT;
    const int kQ0 = (bn0 >> 4) + blockIdx.x * 4 * NT + wn_w * 2 * NT;
#pragma unroll
    for (int mt = 0; mt < MT; ++mt) {
#pragma unroll
      for (int nt = 0; nt < NT; ++nt)
#pragma unroll
        for (int reg = 0; reg < 16; ++reg) {
          int r = (reg & 3) + 8 * (reg >> 2) + 4 * lhi;
          sc[r * SCW + nt * 32 + l31] = __float2bfloat16(acc[mt][nt][reg]);
        }
      __syncthreads();
#pragma unroll
      for (int j = 0; j < 2 * NT; ++j) {
        short8 v = *(const short8*)(sc + l31 * SCW + j * 16 + lhi * 8);
        *(short8*)(Cq + ((size_t)(gQ0 + mt) * CK16 + kQ0 + j) * 512 + lane * 8) = v;
      }
      __syncthreads();
    }
  } else {
    float* C = (float*)Cv + (size_t)z * sC;
    const int ldc = ck16_or_ldc;
    const int bm = blockIdx.y * 64 * MT + wm_w * 32 * MT;
    const int bn = bn0 + blockIdx.x * 64 * NT + wn_w * 32 * NT;
#pragma unroll
    for (int mt = 0; mt < MT; ++mt)
#pragma unroll
      for (int nt = 0; nt < NT; ++nt)
#pragma unroll
        for (int reg = 0; reg < 16; ++reg) {
          int row = bm + mt * 32 + (reg & 3) + 8 * (reg >> 2) + 4 * lhi;
          int col = bn + nt * 32 + l31;
          C[(size_t)row * ldc + col] = acc[mt][nt][reg];
        }
  }
}

extern "C" void kernel_launch(void* const* d_in, const int* in_sizes, int n_in,
                              void* d_out, int out_size, void* d_ws, size_t ws_size,
                              hipStream_t stream) {
  const float* layer1 = (const float*)d_in[0];
  const float* layer2 = (const float*)d_in[1];
  const float* h1 = (const float*)d_in[3];
  const float* h2 = (const float*)d_in[4];
  const float* W = (const float*)d_in[6];
  float* out = (float*)d_out;

  // workspace (high-water 178,880,512 B):
  //   [0 .. 70,254,592)            Pf (8192x4288 bf16, frag)  -- reused for Rf
  //   [70,254,592 .. 107,577,344)  Wt2f (4352x4288 bf16, frag)
  //   [107,577,344 .. 178,880,512) Qf (8192x4352 bf16, frag)
  char* ws = (char*)d_ws;
  __hip_bfloat16* Pf = (__hip_bfloat16*)(ws);
  __hip_bfloat16* Wt2f = (__hip_bfloat16*)(ws + 70254592ULL);
  __hip_bfloat16* Qf = (__hip_bfloat16*)(ws + 107577344ULL);
  __hip_bfloat16* Rf = (__hip_bfloat16*)(ws);  // reuses Pf region after gemm1

  // 1) zero Wt2f pads
  zero_kernel<<<2048, 256, 0, stream>>>((float4*)Wt2f, 37044224LL / 16);
  // 2) W -> fragment layout
  build_wt2f<<<dim3(65, 65), 256, 0, stream>>>(W, Wt2f);
  // 3) Pf
  build_pf<<<NROW / 32, 256, 0, stream>>>(layer1, h1, Pf, K16P);
  // 4a) Qf = Pf @ Wt2f, cols 0..4095: 256x256 blocks, 512 = exactly 2 rounds
  gemm_fraglds<4, 4, 1><<<dim3(16, 32, 1), 256, 0, stream>>>(
      Pf, Wt2f, Qf, K16P, K16D, 0, 0, 0, 0);
  // 4b) cols 4096..4351: 128x128 blocks
  gemm_fraglds<2, 2, 1><<<dim3(2, 64, 1), 256, 0, stream>>>(
      Pf, Wt2f, Qf, K16P, K16D, 4096, 0, 0, 0);
  // 5) Rf (over dead Pf region)
  build_pf<<<NROW / 32, 256, 0, stream>>>(layer2, h2, Rf, K16D);
  // 6) out_n = Qf_n @ Rf_n^T: 256x128 blocks, grid 256 = 1/CU, f32 row-major
  gemm_fraglds<4, 2, 0><<<dim3(8, 4, 8), 256, 0, stream>>>(
      Qf, Rf, out, K16D, 1024, 0, 1024L * DP, 1024L * DP, 1024L * 1024);
}

// Round 6
// 656.088 us; speedup vs baseline: 1.1609x; 1.0089x over previous
//
#include <hip/hip_runtime.h>
#include <hip/hip_bf16.h>

// Qriaffine: out[n,i,j] = sum_{a,b,c,d} l1[n,i,a] W[a,b,c,d] l2[n,j,b] h1[n,i,c] h2[n,j,d]
//
// R6: R5's frag-layout LDS staging (conflict-free, dedup'd) + OCCUPANCY:
// R5's MT=NT=4 needed 256 acc VGPRs -> 1 wave/SIMD -> LDS-read phase and MFMA
// phase serialized (2507 cyc/iter vs 1024 floor). R6 shrinks the wave tile to
// keep acc<=128 and runs 2 blocks/CU (launch_bounds(256,2)) so co-resident
// waves overlap the two pipes (the m114 effect R3 had at 3 blocks/CU).
//   gemm1: MT=2,NT=4  block 128x256, dbuf 48KB, grid 17x64 (no remainder kernel)
//   gemm2: MT=2,NT=2  block 128x128, dbuf 32KB, grid 8x8x8 = 2/CU
//
// Fragment layout for X (rows, K16=K/16): frag (g, kc) = rows [g*32,+32) x
// k [kc*16,+16), 1KB block: elem = ((g*K16 + kc)*64 + lane)*8 + e with
// lane&31 = row%32, lane>>5 = (k%16)/8, e = k%8.

typedef __attribute__((ext_vector_type(8))) short short8;     // 8 bf16
typedef __attribute__((ext_vector_type(16))) float floatx16;  // 32x32 acc

#define KP 4288    // padded (a,c): 268*16
#define DP 4352    // padded (b,d): 272*16
#define NROW 8192  // n*L
#define K16P 268
#define K16D 272

__device__ __forceinline__ void async_ld16(const void* g, void* l) {
  __builtin_amdgcn_global_load_lds(
      (const __attribute__((address_space(1))) unsigned int*)g,
      (__attribute__((address_space(3))) unsigned int*)l, 16, 0, 0);
}

// ---------------- zero helper ----------------
__global__ void zero_kernel(float4* __restrict__ p, long n) {
  long i = (long)blockIdx.x * blockDim.x + threadIdx.x;
  long stride = (long)gridDim.x * blockDim.x;
  float4 z = make_float4(0.f, 0.f, 0.f, 0.f);
  for (; i < n; i += stride) p[i] = z;
}

// ---------------- W[a,b,c,d] -> Wt2 fragment layout (verified R4) ----------------
__global__ void build_wt2f(const float* __restrict__ W, __hip_bfloat16* __restrict__ Bf) {
  const int a = blockIdx.x, b = blockIdx.y;
  const float* src = W + (size_t)(a * 65 + b) * 4225;  // contiguous (c,d) plane
  for (int idx = threadIdx.x; idx < 4225; idx += 256) {
    int c = idx / 65, d = idx - c * 65;
    int bd = b * 65 + d;
    int ac = a * 65 + c;
    int lanef = (bd & 31) + ((ac >> 3) & 1) * 32;
    size_t e = ((size_t)((bd >> 5) * K16P + (ac >> 4)) * 64 + lanef) * 8 + (ac & 7);
    Bf[e] = __float2bfloat16(src[idx]);
  }
}

// ---------------- P/R builder, fragment layout (verified R4) ----------------
__global__ void build_pf(const float* __restrict__ layer, const float* __restrict__ h,
                         __hip_bfloat16* __restrict__ Pf, int K16) {
  const int rb = blockIdx.x;
  const int r0 = rb * 32;
  __shared__ float lv[32][65];
  __shared__ float hv[32][65];
  const int t = threadIdx.x;
  for (int i = t; i < 32 * 64; i += 256)
    lv[i >> 6][i & 63] = layer[(size_t)(r0 + (i >> 6)) * 64 + (i & 63)];
  if (t < 32) lv[t][64] = 1.0f;
  for (int i = t; i < 32 * 65; i += 256) {
    int rr = i / 65, y = i - rr * 65;
    hv[rr][y] = h[(size_t)(r0 + rr) * 65 + y];
  }
  __syncthreads();
  const int lane = t & 63;
  const int rl = lane & 31;
  const int kh = lane >> 5;
  for (int kc = t >> 6; kc < K16; kc += 4) {
    alignas(16) __hip_bfloat16 tmp[8];
#pragma unroll
    for (int e = 0; e < 8; ++e) {
      int k = kc * 16 + kh * 8 + e;
      float v = 0.f;
      if (k < 4225) {
        int x = k / 65, y = k - x * 65;
        v = lv[rl][x] * hv[rl][y];
      }
      tmp[e] = __float2bfloat16(v);
    }
    *(float4*)(Pf + ((size_t)(rb * K16 + kc) * 64 + lane) * 8) = *(const float4*)tmp;
  }
}

// ---------------- frag-staged NT GEMM ----------------
// Block = 64*MT (m) x 64*NT (n), 4 waves as 2x2, wave tile 32*MT x 32*NT of
// mfma_f32_32x32x16_bf16. BK=32 (2 kc per iter). Double-buffered LDS.
// STORE_FRAG=1: C bf16 frag layout (k-dim = global N), CK16 = ck16_or_ldc.
// STORE_FRAG=0: C f32 row-major, ldc = ck16_or_ldc.
template <int MT, int NT, int STORE_FRAG>
__global__ __launch_bounds__(256, 2) void gemm_fraglds(
    const __hip_bfloat16* __restrict__ A, const __hip_bfloat16* __restrict__ B,
    void* __restrict__ Cv, int K16, int ck16_or_ldc, int bn0,
    long sA, long sB, long sC) {
  constexpr int FR = 4 * (MT + NT);  // frag blocks per buffer (2 kc * 2(MT+NT) g)
  constexpr int S = FR / 4;          // DMA slots per thread
  constexpr int BUFSZ = FR * 1024;   // bytes per buffer
  __shared__ char smem[2 * BUFSZ];

  const int z = blockIdx.z;
  const __hip_bfloat16* Ab = A + (size_t)z * sA;
  const __hip_bfloat16* Bb = B + (size_t)z * sB;
  const int t = threadIdx.x;
  const int lane = t & 63;
  const int wave = t >> 6;
  const int l31 = lane & 31;
  const int lhi = lane >> 5;
  const int wm_w = wave >> 1;
  const int wn_w = wave & 1;

  const int Ag0 = blockIdx.y * 2 * MT;              // A 32-row group base
  const int Bg0 = (bn0 >> 5) + blockIdx.x * 2 * NT; // B 32-row group base

  // per-lane source base: byte lane*16 within each 1KB frag block
  const __hip_bfloat16* baseA = Ab + lane * 8;
  const __hip_bfloat16* baseB = Bb + lane * 8;

  floatx16 acc[MT][NT] = {};

  const int NIT = K16 >> 1;

  auto issue = [&](int bufsel, int k16_0) {
    char* lds0 = smem + bufsel * BUFSZ;
#pragma unroll
    for (int s = 0; s < S; ++s) {
      int f = s * 4 + wave;  // wave-uniform
      const __hip_bfloat16* src;
      if (f < 4 * MT) {
        src = baseA + ((size_t)(Ag0 + (f >> 1)) * K16 + k16_0 + (f & 1)) * 512;
      } else {
        int f2 = f - 4 * MT;
        src = baseB + ((size_t)(Bg0 + (f2 >> 1)) * K16 + k16_0 + (f2 & 1)) * 512;
      }
      async_ld16(src, lds0 + f * 1024);
    }
  };

  issue(0, 0);
  for (int it = 0; it < NIT; ++it) {
    __syncthreads();  // drains DMA(it) [compiler emits vmcnt(0) before barrier]
    if (it + 1 < NIT) issue((it + 1) & 1, (it + 1) * 2);  // overlaps compute
    const char* pa = smem + (it & 1) * BUFSZ + lane * 16 + wm_w * MT * 2048;
    const char* pb = smem + (it & 1) * BUFSZ + lane * 16 + 4 * MT * 1024 + wn_w * NT * 2048;
#pragma unroll
    for (int ks = 0; ks < 2; ++ks) {
      short8 af[MT], bfr[NT];
#pragma unroll
      for (int mt = 0; mt < MT; ++mt) af[mt] = *(const short8*)(pa + (mt * 2 + ks) * 1024);
#pragma unroll
      for (int nt = 0; nt < NT; ++nt) bfr[nt] = *(const short8*)(pb + (nt * 2 + ks) * 1024);
#pragma unroll
      for (int mt = 0; mt < MT; ++mt)
#pragma unroll
        for (int nt = 0; nt < NT; ++nt)
          acc[mt][nt] = __builtin_amdgcn_mfma_f32_32x32x16_bf16(af[mt], bfr[nt], acc[mt][nt], 0, 0, 0);
    }
  }

  __syncthreads();  // all compute done; smem reusable as epilogue scratch

  // C/D layout (verified m74/m101): col = lane&31, row = (reg&3)+8*(reg>>2)+4*(lane>>5)
  if (STORE_FRAG) {
    constexpr int SCW = 32 * NT + 8;  // scratch row pitch (bf16), pad breaks conflicts
    __hip_bfloat16* sc = (__hip_bfloat16*)smem + wave * 32 * SCW;
    __hip_bfloat16* Cq = (__hip_bfloat16*)Cv;
    const int CK16 = ck16_or_ldc;
    const int gQ0 = blockIdx.y * 2 * MT + wm_w * MT;
    const int kQ0 = (bn0 >> 4) + blockIdx.x * 4 * NT + wn_w * 2 * NT;
#pragma unroll
    for (int mt = 0; mt < MT; ++mt) {
#pragma unroll
      for (int nt = 0; nt < NT; ++nt)
#pragma unroll
        for (int reg = 0; reg < 16; ++reg) {
          int r = (reg & 3) + 8 * (reg >> 2) + 4 * lhi;
          sc[r * SCW + nt * 32 + l31] = __float2bfloat16(acc[mt][nt][reg]);
        }
      __syncthreads();
#pragma unroll
      for (int j = 0; j < 2 * NT; ++j) {
        short8 v = *(const short8*)(sc + l31 * SCW + j * 16 + lhi * 8);
        *(short8*)(Cq + ((size_t)(gQ0 + mt) * CK16 + kQ0 + j) * 512 + lane * 8) = v;
      }
      __syncthreads();
    }
  } else {
    float* C = (float*)Cv + (size_t)z * sC;
    const int ldc = ck16_or_ldc;
    const int bm = blockIdx.y * 64 * MT + wm_w * 32 * MT;
    const int bn = bn0 + blockIdx.x * 64 * NT + wn_w * 32 * NT;
#pragma unroll
    for (int mt = 0; mt < MT; ++mt)
#pragma unroll
      for (int nt = 0; nt < NT; ++nt)
#pragma unroll
        for (int reg = 0; reg < 16; ++reg) {
          int row = bm + mt * 32 + (reg & 3) + 8 * (reg >> 2) + 4 * lhi;
          int col = bn + nt * 32 + l31;
          C[(size_t)row * ldc + col] = acc[mt][nt][reg];
        }
  }
}

extern "C" void kernel_launch(void* const* d_in, const int* in_sizes, int n_in,
                              void* d_out, int out_size, void* d_ws, size_t ws_size,
                              hipStream_t stream) {
  const float* layer1 = (const float*)d_in[0];
  const float* layer2 = (const float*)d_in[1];
  const float* h1 = (const float*)d_in[3];
  const float* h2 = (const float*)d_in[4];
  const float* W = (const float*)d_in[6];
  float* out = (float*)d_out;

  // workspace (high-water 178,880,512 B):
  //   [0 .. 70,254,592)            Pf (8192x4288 bf16, frag)  -- reused for Rf
  //   [70,254,592 .. 107,577,344)  Wt2f (4352x4288 bf16, frag)
  //   [107,577,344 .. 178,880,512) Qf (8192x4352 bf16, frag)
  char* ws = (char*)d_ws;
  __hip_bfloat16* Pf = (__hip_bfloat16*)(ws);
  __hip_bfloat16* Wt2f = (__hip_bfloat16*)(ws + 70254592ULL);
  __hip_bfloat16* Qf = (__hip_bfloat16*)(ws + 107577344ULL);
  __hip_bfloat16* Rf = (__hip_bfloat16*)(ws);  // reuses Pf region after gemm1

  // 1) zero Wt2f pads
  zero_kernel<<<2048, 256, 0, stream>>>((float4*)Wt2f, 37044224LL / 16);
  // 2) W -> fragment layout
  build_wt2f<<<dim3(65, 65), 256, 0, stream>>>(W, Wt2f);
  // 3) Pf
  build_pf<<<NROW / 32, 256, 0, stream>>>(layer1, h1, Pf, K16P);
  // 4) Qf = Pf @ Wt2f: MT=2,NT=4 block 128x256, grid 17x64 = 1088 blocks
  gemm_fraglds<2, 4, 1><<<dim3(17, 64, 1), 256, 0, stream>>>(
      Pf, Wt2f, Qf, K16P, K16D, 0, 0, 0, 0);
  // 5) Rf (over dead Pf region)
  build_pf<<<NROW / 32, 256, 0, stream>>>(layer2, h2, Rf, K16D);
  // 6) out_n = Qf_n @ Rf_n^T: MT=2,NT=2 block 128x128, grid 8x8x8 = 512 = 2/CU
  gemm_fraglds<2, 2, 0><<<dim3(8, 8, 8), 256, 0, stream>>>(
      Qf, Rf, out, K16D, 1024, 0, 1024L * DP, 1024L * DP, 1024L * 1024);
}